// Round 12
// baseline (260.174 us; speedup 1.0000x reference)
//
#include <hip/hip_runtime.h>
#include <hip/hip_bf16.h>
#include <math.h>

typedef __bf16 bf16;
typedef __attribute__((ext_vector_type(8))) __bf16 bf16x8;
typedef __attribute__((ext_vector_type(2))) float f32x2;
typedef __attribute__((ext_vector_type(4))) float f32x4;
typedef __attribute__((ext_vector_type(4))) unsigned int uint4v;

#define MFMA16(a, b, c) __builtin_amdgcn_mfma_f32_16x16x32_bf16(a, b, c, 0, 0, 0)

// 1/sqrt(96) * log2(e): folded into Qb so attn scores are already in log2 domain.
#define QSCALE 0.14724450f

__device__ inline bf16x8 cvt8(const float* p) {
    f32x4 lo = *(const f32x4*)p;
    f32x4 hi = *(const f32x4*)(p + 4);
    bf16x8 r;
    r[0] = (bf16)lo[0]; r[1] = (bf16)lo[1]; r[2] = (bf16)lo[2]; r[3] = (bf16)lo[3];
    r[4] = (bf16)hi[0]; r[5] = (bf16)hi[1]; r[6] = (bf16)hi[2]; r[7] = (bf16)hi[3];
    return r;
}

// ---------------- Kernel 0: convert all 8 weight matrices fp32 -> bf16 ----------------
// Wb slots: 0 t_cls, 1 d_cls, 2 v_cls, 3 tgl_q, 4 tgl_k, 5 tgl_v, 6 t_tok, 7 v_patch

struct WPtrs { const float* W[8]; };

__global__ __launch_bounds__(256) void cvtw_kernel(WPtrs wp, bf16* __restrict__ Wb) {
    int j   = blockIdx.x / 48;
    int blk = blockIdx.x - j * 48;
    int idx = (blk * 256 + threadIdx.x) * 4;
    f32x4 v = *(const f32x4*)(wp.W[j] + idx);
    bf16* dst = Wb + j * 49152 + idx;
    dst[0] = (bf16)v[0]; dst[1] = (bf16)v[1]; dst[2] = (bf16)v[2]; dst[3] = (bf16)v[3];
}

// ---------------- Kernel 1: all 8 projections — K-SPLIT across waves ----------------
// Block = 256 thr = 4 waves: (nh = col-half 48, kh = K-half 256).
// Each wave: 8 K-iterations (7 loads/iter, chain HALVED vs R9/R11's 16).
// kh=1 partial accs -> LDS; kh=0 reduces, bias, l2norm (cross-nh via sx), stores.
// R9/R10/R11 lesson: compiler pins ~small load window/wave -> the serial K-chain
// length sets proj time; K-split halves it and doubles concurrent chains.
// No min-waves bound (R6/R10: caps starve VGPRs / spill).

struct ProjParams {
    const float* src[8];
    const float* B[8];
    void* dst[8];
    const bf16* Wb;
};

__global__ __launch_bounds__(256) void proj_kernel(ProjParams p) {
    int g   = blockIdx.x;
    int tid = threadIdx.x;
    int w2 = tid >> 6;
    int nh = w2 & 1, kh = w2 >> 1;
    int lane = tid & 63;
    int m = lane & 15, quad = lane >> 4;

    // jobs: 0:t 1:d 2:v 3:Q 4:K 5:V 6:t_tok 7:v_pat
    // 32-row groups: 2,2,2,256,256,256,256,392 ; cum 2,4,6,262,518,774,1030,1422
    int job = 0, base = 0;
    if (g >= 2)    { job = 1; base = 2; }
    if (g >= 4)    { job = 2; base = 4; }
    if (g >= 6)    { job = 3; base = 6; }
    if (g >= 262)  { job = 4; base = 262; }
    if (g >= 518)  { job = 5; base = 518; }
    if (g >= 774)  { job = 6; base = 774; }
    if (g >= 1030) { job = 7; base = 1030; }
    int r0 = (g - base) << 5;

    const float* X  = p.src[job];
    const bf16*  wb = p.Wb + job * 49152 + (size_t)(nh * 48 + m) * 512 + kh * 256 + quad * 8;
    const float* x0 = X + (size_t)(r0 + m) * 512 + kh * 256 + quad * 8;
    const float* x1 = x0 + 16 * 512;

    f32x4 acc[2][3] = {};
    #pragma unroll
    for (int kk = 0; kk < 256; kk += 32) {
        bf16x8 a0 = cvt8(x0 + kk);
        bf16x8 a1 = cvt8(x1 + kk);
        #pragma unroll
        for (int nt = 0; nt < 3; nt++) {
            bf16x8 b = *(const bf16x8*)(wb + nt * 8192 + kk);
            acc[0][nt] = MFMA16(a0, b, acc[0][nt]);
            acc[1][nt] = MFMA16(a1, b, acc[1][nt]);
        }
    }

    __shared__ float red[2 * 64 * 24];      // [nh][lane][24] partial accs (12 KB)
    __shared__ float sx[2][2][16];          // [nh][t2][quad*4+r] cross-nh norm
    float* myred = red + (nh * 64 + lane) * 24;
    if (kh) {
        #pragma unroll
        for (int t2 = 0; t2 < 2; t2++)
            #pragma unroll
            for (int nt = 0; nt < 3; nt++)
                *(f32x4*)(myred + (t2 * 3 + nt) * 4) = acc[t2][nt];
    }
    __syncthreads();

    bool norm = (job < 3) || (job >= 6);
    const float* Bv = p.B[job];
    if (!kh) {
        #pragma unroll
        for (int t2 = 0; t2 < 2; t2++)
            #pragma unroll
            for (int nt = 0; nt < 3; nt++) {
                f32x4 o = *(const f32x4*)(myred + (t2 * 3 + nt) * 4);
                float bb = Bv[nh * 48 + nt * 16 + m];
                acc[t2][nt][0] += o[0] + bb; acc[t2][nt][1] += o[1] + bb;
                acc[t2][nt][2] += o[2] + bb; acc[t2][nt][3] += o[3] + bb;
            }
        if (norm) {
            float ss[2][4];
            #pragma unroll
            for (int t2 = 0; t2 < 2; t2++)
                #pragma unroll
                for (int r = 0; r < 4; r++) {
                    float s = 0.0f;
                    #pragma unroll
                    for (int nt = 0; nt < 3; nt++) s += acc[t2][nt][r] * acc[t2][nt][r];
                    s += __shfl_xor(s, 1); s += __shfl_xor(s, 2);
                    s += __shfl_xor(s, 4); s += __shfl_xor(s, 8);
                    ss[t2][r] = s;
                }
            if (m == 0) {
                #pragma unroll
                for (int t2 = 0; t2 < 2; t2++)
                    #pragma unroll
                    for (int r = 0; r < 4; r++)
                        sx[nh][t2][quad * 4 + r] = ss[t2][r];
            }
            // stash own ss in acc-free regs via re-use: recompute after barrier instead
        }
    }
    __syncthreads();
    if (!kh) {
        if (norm) {
            #pragma unroll
            for (int t2 = 0; t2 < 2; t2++)
                #pragma unroll
                for (int r = 0; r < 4; r++) {
                    float s = 0.0f;
                    #pragma unroll
                    for (int nt = 0; nt < 3; nt++) s += acc[t2][nt][r] * acc[t2][nt][r];
                    s += __shfl_xor(s, 1); s += __shfl_xor(s, 2);
                    s += __shfl_xor(s, 4); s += __shfl_xor(s, 8);
                    float tot = s + sx[1 - nh][t2][quad * 4 + r];
                    float inv = 1.0f / fmaxf(sqrtf(tot), 1e-6f);
                    #pragma unroll
                    for (int nt = 0; nt < 3; nt++) acc[t2][nt][r] *= inv;
                }
        } else if (job == 3) {
            #pragma unroll
            for (int t2 = 0; t2 < 2; t2++)
                #pragma unroll
                for (int nt = 0; nt < 3; nt++) {
                    acc[t2][nt][0] *= QSCALE; acc[t2][nt][1] *= QSCALE;
                    acc[t2][nt][2] *= QSCALE; acc[t2][nt][3] *= QSCALE;
                }
        }
        if (job < 3) {
            float* dst = (float*)p.dst[job];
            #pragma unroll
            for (int t2 = 0; t2 < 2; t2++)
                #pragma unroll
                for (int r = 0; r < 4; r++)
                    #pragma unroll
                    for (int nt = 0; nt < 3; nt++)
                        dst[(size_t)(r0 + t2 * 16 + quad * 4 + r) * 96 + nh * 48 + nt * 16 + m] = acc[t2][nt][r];
        } else {
            bf16* dst = (bf16*)p.dst[job];
            #pragma unroll
            for (int t2 = 0; t2 < 2; t2++)
                #pragma unroll
                for (int r = 0; r < 4; r++)
                    #pragma unroll
                    for (int nt = 0; nt < 3; nt++)
                        dst[(size_t)(r0 + t2 * 16 + quad * 4 + r) * 96 + nh * 48 + nt * 16 + m] = (bf16)acc[t2][nt][r];
        }
    }
}

// ---------------- Kernel 2: TGL attention, (b, c-group-of-4) blocks -> ctx ----------
// Q A-fragments loaded ONCE into registers (24 VGPRs), reused across 4 c's.
// K_c staged in LDS per ci. Scores log2-scaled (QSCALE in Qb); softmax without
// max-subtraction. Writes pre-LN ctx; LN/l2n/dots in epi_kernel.

__global__ __launch_bounds__(256) void attn_kernel(
    const bf16* __restrict__ Qg, const bf16* __restrict__ Kg, const bf16* __restrict__ Vg,
    float* __restrict__ Ctx)
{
    int b  = blockIdx.x >> 4;
    int cg = blockIdx.x & 15;
    int tid = threadIdx.x, lane = tid & 63, w = tid >> 6;
    int m = lane & 15, quad = lane >> 4;
    const bf16* Q = Qg + (size_t)b * (128 * 96);

    bf16x8 qa0[3], qa1[3];
    #pragma unroll
    for (int i = 0; i < 3; i++) {
        qa0[i] = *(const bf16x8*)(Q + (size_t)(w * 32 + m) * 96 + i * 32 + quad * 8);
        qa1[i] = *(const bf16x8*)(Q + (size_t)(w * 32 + 16 + m) * 96 + i * 32 + quad * 8);
    }

    __shared__ __align__(16) bf16 Klds[128 * 104];
    __shared__ float wsum4[4][128];
    __shared__ float wk[128];
    __shared__ float ctxp[4][96];

    for (int ci = 0; ci < 4; ci++) {
        int c = cg * 4 + ci;
        const bf16* K = Kg + (size_t)c * (128 * 96);
        const bf16* V = Vg + (size_t)c * (128 * 96);
        #pragma unroll
        for (int it = 0; it < 6; it++) {
            int ch = it * 256 + tid;
            int row = ch / 12, seg = ch - row * 12;
            *(uint4v*)(Klds + row * 104 + seg * 8) = *(const uint4v*)(K + ch * 8);
        }
        __syncthreads();

        f32x4 acc[2][8] = {};
        #pragma unroll
        for (int kki = 0; kki < 3; kki++) {
            #pragma unroll
            for (int nt = 0; nt < 8; nt++) {
                bf16x8 bb = *(const bf16x8*)(Klds + (nt * 16 + m) * 104 + kki * 32 + quad * 8);
                acc[0][nt] = MFMA16(qa0[kki], bb, acc[0][nt]);
                acc[1][nt] = MFMA16(qa1[kki], bb, acc[1][nt]);
            }
        }
        float wpart[8];
        #pragma unroll
        for (int nt = 0; nt < 8; nt++) wpart[nt] = 0.0f;
        #pragma unroll
        for (int mt = 0; mt < 2; mt++) {
            #pragma unroll
            for (int r = 0; r < 4; r++) {
                float tv[8]; float s = 0.0f;
                #pragma unroll
                for (int nt = 0; nt < 8; nt++) { tv[nt] = exp2f(acc[mt][nt][r]); s += tv[nt]; }
                s += __shfl_xor(s, 1); s += __shfl_xor(s, 2);
                s += __shfl_xor(s, 4); s += __shfl_xor(s, 8);
                float inv = 1.0f / s;
                #pragma unroll
                for (int nt = 0; nt < 8; nt++) wpart[nt] += tv[nt] * inv;
            }
        }
        #pragma unroll
        for (int nt = 0; nt < 8; nt++) {
            wpart[nt] += __shfl_xor(wpart[nt], 16);
            wpart[nt] += __shfl_xor(wpart[nt], 32);
        }
        if (lane < 16) {
            #pragma unroll
            for (int nt = 0; nt < 8; nt++) wsum4[w][nt * 16 + lane] = wpart[nt];
        }
        __syncthreads();
        if (tid < 128) wk[tid] = wsum4[0][tid] + wsum4[1][tid] + wsum4[2][tid] + wsum4[3][tid];
        __syncthreads();
        {
            float c0 = 0.0f, c1 = 0.0f;
            if (lane < 48) {
                #pragma unroll 4
                for (int r = 0; r < 32; r++) {
                    int k = w * 32 + r;
                    unsigned u = *(const unsigned*)(V + (size_t)k * 96 + lane * 2);
                    float lo = __uint_as_float(u << 16);
                    float hi = __uint_as_float(u & 0xffff0000u);
                    float wkk = wk[k];
                    c0 += wkk * lo; c1 += wkk * hi;
                }
                ctxp[w][lane * 2]     = c0;
                ctxp[w][lane * 2 + 1] = c1;
            }
        }
        __syncthreads();
        if (tid < 96)
            Ctx[(size_t)(b * 64 + c) * 96 + tid] =
                (ctxp[0][tid] + ctxp[1][tid] + ctxp[2][tid] + ctxp[3][tid]) * (1.0f / 128.0f);
    }
}

// ---------------- Kernel 3: CLL, c-major with 8-b batch ----------------
// Block = (c, bgroup): stage v_pat_c once (196x104 LDS), loop 8 b-tiles of t_tok.
// DEFAULT launch_bounds: acc[2][13]=104 regs must stay in registers (R6 spill lesson).

__global__ __launch_bounds__(256) void cll_kernel(
    const bf16* __restrict__ Tt, const bf16* __restrict__ Vp, float* __restrict__ S_CLL)
{
    int c = blockIdx.x >> 3, bg = blockIdx.x & 7;
    int tid = threadIdx.x, lane = tid & 63, w = tid >> 6;
    int m = lane & 15, quad = lane >> 4;
    const bf16* P = Vp + (size_t)c * (196 * 96);

    __shared__ __align__(16) bf16 Plds[196 * 104];
    __shared__ float red[8][4];
    for (int ch = tid; ch < 2352; ch += 256) {
        int row = ch / 12, seg = ch - row * 12;
        *(uint4v*)(Plds + row * 104 + seg * 8) = *(const uint4v*)(P + ch * 8);
    }
    int rofs[13];
    #pragma unroll
    for (int nt = 0; nt < 13; nt++) {
        int r = nt * 16 + m; if (r > 195) r = 195;
        rofs[nt] = r * 104;
    }
    __syncthreads();

    for (int bi = 0; bi < 8; bi++) {
        const bf16* T = Tt + (size_t)(bg * 8 + bi) * (128 * 96);
        f32x4 acc[2][13] = {};
        #pragma unroll
        for (int kk = 0; kk < 96; kk += 32) {
            bf16x8 a0 = *(const bf16x8*)(T + (size_t)(w * 32 + m) * 96 + kk + quad * 8);
            bf16x8 a1 = *(const bf16x8*)(T + (size_t)(w * 32 + 16 + m) * 96 + kk + quad * 8);
            #pragma unroll
            for (int nt = 0; nt < 13; nt++) {
                bf16x8 bb = *(const bf16x8*)(Plds + rofs[nt] + kk + quad * 8);
                acc[0][nt] = MFMA16(a0, bb, acc[0][nt]);
                acc[1][nt] = MFMA16(a1, bb, acc[1][nt]);
            }
        }
        float mx = -3.4e38f;
        #pragma unroll
        for (int mt = 0; mt < 2; mt++)
            #pragma unroll
            for (int nt = 0; nt < 13; nt++)
                #pragma unroll
                for (int r = 0; r < 4; r++) mx = fmaxf(mx, acc[mt][nt][r]);
        #pragma unroll
        for (int d = 1; d < 64; d <<= 1) mx = fmaxf(mx, __shfl_xor(mx, d));
        if (lane == 0) red[bi][w] = mx;
    }
    __syncthreads();
    if (tid < 8)
        S_CLL[(size_t)(bg * 8 + tid) * 64 + c] =
            fmaxf(fmaxf(red[tid][0], red[tid][1]), fmaxf(red[tid][2], red[tid][3]));
}

// ---------------- Kernel 4: epilogue — LN + l2n + dots + combine ----------------
// One wave per (i,j): LN(ctx), l2n, S_TGL = d_i · y (row index!), tg = t_i · d_j,
// cg = t_i · v_j, combine with S_CLL.

__global__ __launch_bounds__(256) void epi_kernel(
    const float* __restrict__ Ctx, const float* __restrict__ t, const float* __restrict__ d,
    const float* __restrict__ v, const float* __restrict__ S_CLL,
    const float* __restrict__ ln_g, const float* __restrict__ ln_b,
    float* __restrict__ out)
{
    int pr = blockIdx.x * 4 + (threadIdx.x >> 6);
    int lane = threadIdx.x & 63;
    int i = pr >> 6, j = pr & 63;
    bool act = lane < 48;

    float c0 = 0, c1 = 0, t0 = 0, t1 = 0;
    float dj0 = 0, dj1 = 0, di0 = 0, di1 = 0, v0 = 0, v1 = 0, g0 = 0, g1 = 0, bb0 = 0, bb1 = 0;
    if (act) {
        f32x2 cc  = *(const f32x2*)(Ctx + (size_t)pr * 96 + lane * 2);
        f32x2 tt  = *(const f32x2*)(t + i * 96 + lane * 2);
        f32x2 ddj = *(const f32x2*)(d + j * 96 + lane * 2);
        f32x2 ddi = *(const f32x2*)(d + i * 96 + lane * 2);
        f32x2 vv  = *(const f32x2*)(v + j * 96 + lane * 2);
        f32x2 gg  = *(const f32x2*)(ln_g + lane * 2);
        f32x2 bbv = *(const f32x2*)(ln_b + lane * 2);
        c0 = cc[0]; c1 = cc[1]; t0 = tt[0]; t1 = tt[1];
        dj0 = ddj[0]; dj1 = ddj[1]; di0 = ddi[0]; di1 = ddi[1];
        v0 = vv[0]; v1 = vv[1];
        g0 = gg[0]; g1 = gg[1]; bb0 = bbv[0]; bb1 = bbv[1];
    }
    float s = c0 + c1;
    #pragma unroll
    for (int k = 1; k < 64; k <<= 1) s += __shfl_xor(s, k);
    float mean = s * (1.0f / 96.0f);
    float e0 = act ? (c0 - mean) : 0.0f;
    float e1 = act ? (c1 - mean) : 0.0f;
    float q = e0 * e0 + e1 * e1;
    #pragma unroll
    for (int k = 1; k < 64; k <<= 1) q += __shfl_xor(q, k);
    float rstd = rsqrtf(q * (1.0f / 96.0f) + 1e-5f);
    float y0 = act ? (e0 * rstd * g0 + bb0) : 0.0f;
    float y1 = act ? (e1 * rstd * g1 + bb1) : 0.0f;
    float dot = y0 * di0 + y1 * di1;   // S_TGL uses d_i
    float ssq = y0 * y0 + y1 * y1;
    float tg  = t0 * dj0 + t1 * dj1;   // S_TGG uses d_j
    float cg  = t0 * v0 + t1 * v1;
    #pragma unroll
    for (int k = 1; k < 64; k <<= 1) {
        dot += __shfl_xor(dot, k); ssq += __shfl_xor(ssq, k);
        tg  += __shfl_xor(tg, k);  cg  += __shfl_xor(cg, k);
    }
    if (lane == 0) {
        float stgl = dot / fmaxf(sqrtf(ssq), 1e-6f);
        out[pr] = 0.5f * (tg + stgl) + 0.5f * (cg + S_CLL[pr]);
    }
}

// ---------------- launch ----------------

extern "C" void kernel_launch(void* const* d_in, const int* in_sizes, int n_in,
                              void* d_out, int out_size, void* d_ws, size_t ws_size,
                              hipStream_t stream)
{
    (void)in_sizes; (void)n_in; (void)out_size; (void)ws_size;
    char* ws = (char*)d_ws;
    float* t     = (float*)(ws + 0);               // 64*96 f32
    float* d     = (float*)(ws + 24576);
    float* v     = (float*)(ws + 49152);
    float* S_CLL = (float*)(ws + 90112);
    bf16* Wb = (bf16*)(ws + 106496);               // 8*96*512 bf16
    bf16* Qb = (bf16*)(ws + 892928);               // 8192*96 bf16
    bf16* Kb = (bf16*)(ws + 892928 + 1572864);
    bf16* Vb = (bf16*)(ws + 892928 + 2 * 1572864);
    bf16* Tt = (bf16*)(ws + 892928 + 3 * 1572864);
    bf16* Vp = (bf16*)(ws + 892928 + 4 * 1572864);         // 12544*96 bf16 = 2408448 B
    float* Ctx = (float*)(ws + 892928 + 4 * 1572864 + 2408448); // 4096*96 f32 = 1572864 B

    WPtrs wp;
    wp.W[0] = (const float*)d_in[6];   // W_t_cls
    wp.W[1] = (const float*)d_in[8];   // W_d_cls
    wp.W[2] = (const float*)d_in[10];  // W_v_cls
    wp.W[3] = (const float*)d_in[16];  // W_tgl_q
    wp.W[4] = (const float*)d_in[18];  // W_tgl_k
    wp.W[5] = (const float*)d_in[20];  // W_tgl_v
    wp.W[6] = (const float*)d_in[12];  // W_t_tok
    wp.W[7] = (const float*)d_in[14];  // W_v_patch
    hipLaunchKernelGGL(cvtw_kernel, dim3(384), dim3(256), 0, stream, wp, Wb);

    ProjParams pp;
    pp.Wb = Wb;
    pp.src[0] = (const float*)d_in[2];  pp.B[0] = (const float*)d_in[7];  pp.dst[0] = t;   // t_cls
    pp.src[1] = (const float*)d_in[0];  pp.B[1] = (const float*)d_in[9];  pp.dst[1] = d;   // d_cls
    pp.src[2] = (const float*)d_in[4];  pp.B[2] = (const float*)d_in[11]; pp.dst[2] = v;   // v_cls
    pp.src[3] = (const float*)d_in[1];  pp.B[3] = (const float*)d_in[17]; pp.dst[3] = Qb;  // Q (scaled)
    pp.src[4] = (const float*)d_in[3];  pp.B[4] = (const float*)d_in[19]; pp.dst[4] = Kb;  // K
    pp.src[5] = (const float*)d_in[3];  pp.B[5] = (const float*)d_in[21]; pp.dst[5] = Vb;  // V
    pp.src[6] = (const float*)d_in[3];  pp.B[6] = (const float*)d_in[13]; pp.dst[6] = Tt;  // t_tok
    pp.src[7] = (const float*)d_in[5];  pp.B[7] = (const float*)d_in[15]; pp.dst[7] = Vp;  // v_patch
    hipLaunchKernelGGL(proj_kernel, dim3(1422), dim3(256), 0, stream, pp);

    hipLaunchKernelGGL(attn_kernel, dim3(1024), dim3(256), 0, stream,
                       (const bf16*)Qb, (const bf16*)Kb, (const bf16*)Vb, Ctx);
    hipLaunchKernelGGL(cll_kernel, dim3(512), dim3(256), 0, stream,
                       (const bf16*)Tt, (const bf16*)Vp, S_CLL);
    hipLaunchKernelGGL(epi_kernel, dim3(1024), dim3(256), 0, stream,
                       (const float*)Ctx, (const float*)t, (const float*)d, (const float*)v,
                       (const float*)S_CLL, (const float*)d_in[22], (const float*)d_in[23],
                       (float*)d_out);
}

// Round 13
// 238.690 us; speedup vs baseline: 1.0900x; 1.0900x over previous
//
#include <hip/hip_runtime.h>
#include <hip/hip_bf16.h>
#include <math.h>

typedef __bf16 bf16;
typedef __attribute__((ext_vector_type(8))) __bf16 bf16x8;
typedef __attribute__((ext_vector_type(2))) float f32x2;
typedef __attribute__((ext_vector_type(4))) float f32x4;
typedef __attribute__((ext_vector_type(4))) unsigned int uint4v;

#define MFMA16(a, b, c) __builtin_amdgcn_mfma_f32_16x16x32_bf16(a, b, c, 0, 0, 0)

// 1/sqrt(96) * log2(e): folded into Qb so attn scores are already in log2 domain.
#define QSCALE 0.14724450f

__device__ inline bf16x8 cvt8(const float* p) {
    f32x4 lo = *(const f32x4*)p;
    f32x4 hi = *(const f32x4*)(p + 4);
    bf16x8 r;
    r[0] = (bf16)lo[0]; r[1] = (bf16)lo[1]; r[2] = (bf16)lo[2]; r[3] = (bf16)lo[3];
    r[4] = (bf16)hi[0]; r[5] = (bf16)hi[1]; r[6] = (bf16)hi[2]; r[7] = (bf16)hi[3];
    return r;
}

// ---------------- Kernel 0: convert all 8 weight matrices fp32 -> bf16 ----------------
// Wb slots: 0 t_cls, 1 d_cls, 2 v_cls, 3 tgl_q, 4 tgl_k, 5 tgl_v, 6 t_tok, 7 v_patch

struct WPtrs { const float* W[8]; };

__global__ __launch_bounds__(256) void cvtw_kernel(WPtrs wp, bf16* __restrict__ Wb) {
    int j   = blockIdx.x / 48;
    int blk = blockIdx.x - j * 48;
    int idx = (blk * 256 + threadIdx.x) * 4;
    f32x4 v = *(const f32x4*)(wp.W[j] + idx);
    bf16* dst = Wb + j * 49152 + idx;
    dst[0] = (bf16)v[0]; dst[1] = (bf16)v[1]; dst[2] = (bf16)v[2]; dst[3] = (bf16)v[3];
}

// ---------------- Kernel 1: all 8 projections — K-SPLIT across waves ----------------
// Block = 256 thr = 4 waves: (nh = col-half 48, kh = K-half 256).
// Each wave: 8 K-iterations; kh=1 partial accs -> LDS; kh=0 reduces + bias + norm.

struct ProjParams {
    const float* src[8];
    const float* B[8];
    void* dst[8];
    const bf16* Wb;
};

__global__ __launch_bounds__(256) void proj_kernel(ProjParams p) {
    int g   = blockIdx.x;
    int tid = threadIdx.x;
    int w2 = tid >> 6;
    int nh = w2 & 1, kh = w2 >> 1;
    int lane = tid & 63;
    int m = lane & 15, quad = lane >> 4;

    int job = 0, base = 0;
    if (g >= 2)    { job = 1; base = 2; }
    if (g >= 4)    { job = 2; base = 4; }
    if (g >= 6)    { job = 3; base = 6; }
    if (g >= 262)  { job = 4; base = 262; }
    if (g >= 518)  { job = 5; base = 518; }
    if (g >= 774)  { job = 6; base = 774; }
    if (g >= 1030) { job = 7; base = 1030; }
    int r0 = (g - base) << 5;

    const float* X  = p.src[job];
    const bf16*  wb = p.Wb + job * 49152 + (size_t)(nh * 48 + m) * 512 + kh * 256 + quad * 8;
    const float* x0 = X + (size_t)(r0 + m) * 512 + kh * 256 + quad * 8;
    const float* x1 = x0 + 16 * 512;

    f32x4 acc[2][3] = {};
    #pragma unroll
    for (int kk = 0; kk < 256; kk += 32) {
        bf16x8 a0 = cvt8(x0 + kk);
        bf16x8 a1 = cvt8(x1 + kk);
        #pragma unroll
        for (int nt = 0; nt < 3; nt++) {
            bf16x8 b = *(const bf16x8*)(wb + nt * 8192 + kk);
            acc[0][nt] = MFMA16(a0, b, acc[0][nt]);
            acc[1][nt] = MFMA16(a1, b, acc[1][nt]);
        }
    }

    __shared__ float red[2 * 64 * 24];
    __shared__ float sx[2][2][16];
    float* myred = red + (nh * 64 + lane) * 24;
    if (kh) {
        #pragma unroll
        for (int t2 = 0; t2 < 2; t2++)
            #pragma unroll
            for (int nt = 0; nt < 3; nt++)
                *(f32x4*)(myred + (t2 * 3 + nt) * 4) = acc[t2][nt];
    }
    __syncthreads();

    bool norm = (job < 3) || (job >= 6);
    const float* Bv = p.B[job];
    if (!kh) {
        #pragma unroll
        for (int t2 = 0; t2 < 2; t2++)
            #pragma unroll
            for (int nt = 0; nt < 3; nt++) {
                f32x4 o = *(const f32x4*)(myred + (t2 * 3 + nt) * 4);
                float bb = Bv[nh * 48 + nt * 16 + m];
                acc[t2][nt][0] += o[0] + bb; acc[t2][nt][1] += o[1] + bb;
                acc[t2][nt][2] += o[2] + bb; acc[t2][nt][3] += o[3] + bb;
            }
        if (norm) {
            float ss[2][4];
            #pragma unroll
            for (int t2 = 0; t2 < 2; t2++)
                #pragma unroll
                for (int r = 0; r < 4; r++) {
                    float s = 0.0f;
                    #pragma unroll
                    for (int nt = 0; nt < 3; nt++) s += acc[t2][nt][r] * acc[t2][nt][r];
                    s += __shfl_xor(s, 1); s += __shfl_xor(s, 2);
                    s += __shfl_xor(s, 4); s += __shfl_xor(s, 8);
                    ss[t2][r] = s;
                }
            if (m == 0) {
                #pragma unroll
                for (int t2 = 0; t2 < 2; t2++)
                    #pragma unroll
                    for (int r = 0; r < 4; r++)
                        sx[nh][t2][quad * 4 + r] = ss[t2][r];
            }
        }
    }
    __syncthreads();
    if (!kh) {
        if (norm) {
            #pragma unroll
            for (int t2 = 0; t2 < 2; t2++)
                #pragma unroll
                for (int r = 0; r < 4; r++) {
                    float s = 0.0f;
                    #pragma unroll
                    for (int nt = 0; nt < 3; nt++) s += acc[t2][nt][r] * acc[t2][nt][r];
                    s += __shfl_xor(s, 1); s += __shfl_xor(s, 2);
                    s += __shfl_xor(s, 4); s += __shfl_xor(s, 8);
                    float tot = s + sx[1 - nh][t2][quad * 4 + r];
                    float inv = 1.0f / fmaxf(sqrtf(tot), 1e-6f);
                    #pragma unroll
                    for (int nt = 0; nt < 3; nt++) acc[t2][nt][r] *= inv;
                }
        } else if (job == 3) {
            #pragma unroll
            for (int t2 = 0; t2 < 2; t2++)
                #pragma unroll
                for (int nt = 0; nt < 3; nt++) {
                    acc[t2][nt][0] *= QSCALE; acc[t2][nt][1] *= QSCALE;
                    acc[t2][nt][2] *= QSCALE; acc[t2][nt][3] *= QSCALE;
                }
        }
        if (job < 3) {
            float* dst = (float*)p.dst[job];
            #pragma unroll
            for (int t2 = 0; t2 < 2; t2++)
                #pragma unroll
                for (int r = 0; r < 4; r++)
                    #pragma unroll
                    for (int nt = 0; nt < 3; nt++)
                        dst[(size_t)(r0 + t2 * 16 + quad * 4 + r) * 96 + nh * 48 + nt * 16 + m] = acc[t2][nt][r];
        } else {
            bf16* dst = (bf16*)p.dst[job];
            #pragma unroll
            for (int t2 = 0; t2 < 2; t2++)
                #pragma unroll
                for (int r = 0; r < 4; r++)
                    #pragma unroll
                    for (int nt = 0; nt < 3; nt++)
                        dst[(size_t)(r0 + t2 * 16 + quad * 4 + r) * 96 + nh * 48 + nt * 16 + m] = (bf16)acc[t2][nt][r];
        }
    }
}

// ---------------- Kernel 2: TGL attention per (b,c) pair -> ctx[96] ----------------
// EXACT R9 form (4096 independent blocks — R12 proved pair-batching loses TLP).
// LDS K-staging; scores log2-scaled (QSCALE in Qb); softmax w/o max-subtraction.

__global__ __launch_bounds__(256) void attn_kernel(
    const bf16* __restrict__ Qg, const bf16* __restrict__ Kg, const bf16* __restrict__ Vg,
    float* __restrict__ Ctx)
{
    int pr = blockIdx.x;
    int b = pr >> 6, c = pr & 63;
    int tid = threadIdx.x, lane = tid & 63, w = tid >> 6;
    int m = lane & 15, quad = lane >> 4;
    const bf16* Q = Qg + (size_t)b * (128 * 96);
    const bf16* K = Kg + (size_t)c * (128 * 96);
    const bf16* V = Vg + (size_t)c * (128 * 96);

    __shared__ __align__(16) bf16 Klds[128 * 104];
    #pragma unroll
    for (int it = 0; it < 6; it++) {
        int ch = it * 256 + tid;
        int row = ch / 12, seg = ch - row * 12;
        *(uint4v*)(Klds + row * 104 + seg * 8) = *(const uint4v*)(K + ch * 8);
    }
    __syncthreads();

    f32x4 acc[2][8] = {};
    #pragma unroll
    for (int kk = 0; kk < 96; kk += 32) {
        bf16x8 a0 = *(const bf16x8*)(Q + (size_t)(w * 32 + m) * 96 + kk + quad * 8);
        bf16x8 a1 = *(const bf16x8*)(Q + (size_t)(w * 32 + 16 + m) * 96 + kk + quad * 8);
        #pragma unroll
        for (int nt = 0; nt < 8; nt++) {
            bf16x8 bb = *(const bf16x8*)(Klds + (nt * 16 + m) * 104 + kk + quad * 8);
            acc[0][nt] = MFMA16(a0, bb, acc[0][nt]);
            acc[1][nt] = MFMA16(a1, bb, acc[1][nt]);
        }
    }
    float wpart[8];
    #pragma unroll
    for (int nt = 0; nt < 8; nt++) wpart[nt] = 0.0f;
    #pragma unroll
    for (int mt = 0; mt < 2; mt++) {
        #pragma unroll
        for (int r = 0; r < 4; r++) {
            float tv[8]; float s = 0.0f;
            #pragma unroll
            for (int nt = 0; nt < 8; nt++) { tv[nt] = exp2f(acc[mt][nt][r]); s += tv[nt]; }
            s += __shfl_xor(s, 1); s += __shfl_xor(s, 2);
            s += __shfl_xor(s, 4); s += __shfl_xor(s, 8);
            float inv = 1.0f / s;
            #pragma unroll
            for (int nt = 0; nt < 8; nt++) wpart[nt] += tv[nt] * inv;
        }
    }
    #pragma unroll
    for (int nt = 0; nt < 8; nt++) {
        wpart[nt] += __shfl_xor(wpart[nt], 16);
        wpart[nt] += __shfl_xor(wpart[nt], 32);
    }
    __shared__ float wsum4[4][128];
    __shared__ float wk[128];
    __shared__ float ctxp[4][96];
    if (lane < 16) {
        #pragma unroll
        for (int nt = 0; nt < 8; nt++) wsum4[w][nt * 16 + lane] = wpart[nt];
    }
    __syncthreads();
    if (tid < 128) wk[tid] = wsum4[0][tid] + wsum4[1][tid] + wsum4[2][tid] + wsum4[3][tid];
    __syncthreads();
    {
        float c0 = 0.0f, c1 = 0.0f;
        if (lane < 48) {
            #pragma unroll 4
            for (int r = 0; r < 32; r++) {
                int k = w * 32 + r;
                unsigned u = *(const unsigned*)(V + (size_t)k * 96 + lane * 2);
                float lo = __uint_as_float(u << 16);
                float hi = __uint_as_float(u & 0xffff0000u);
                float wkk = wk[k];
                c0 += wkk * lo; c1 += wkk * hi;
            }
            ctxp[w][lane * 2]     = c0;
            ctxp[w][lane * 2 + 1] = c1;
        }
    }
    __syncthreads();
    if (tid < 96)
        Ctx[(size_t)pr * 96 + tid] =
            (ctxp[0][tid] + ctxp[1][tid] + ctxp[2][tid] + ctxp[3][tid]) * (1.0f / 128.0f);
}

// ---------------- Kernel 3: CLL + fused epilogue ----------------
// Block = (c, bgroup): stage v_pat_c once, loop 8 b-tiles of t_tok (max-sim),
// then each wave runs the LN/l2n/dots epilogue for 2 of the block's 8 pairs and
// writes d_out directly (replaces epi_kernel; one less dispatch + gap).
// S_TGL uses d_i (row); tg uses d_j. DEFAULT launch_bounds (R6 spill lesson).

__global__ __launch_bounds__(256) void cll_kernel(
    const bf16* __restrict__ Tt, const bf16* __restrict__ Vp,
    const float* __restrict__ Ctx, const float* __restrict__ t,
    const float* __restrict__ d, const float* __restrict__ v,
    const float* __restrict__ ln_g, const float* __restrict__ ln_b,
    float* __restrict__ out)
{
    int c = blockIdx.x >> 3, bg = blockIdx.x & 7;
    int tid = threadIdx.x, lane = tid & 63, w = tid >> 6;
    int m = lane & 15, quad = lane >> 4;
    const bf16* P = Vp + (size_t)c * (196 * 96);

    __shared__ __align__(16) bf16 Plds[196 * 104];
    __shared__ float red[8][4];
    for (int ch = tid; ch < 2352; ch += 256) {
        int row = ch / 12, seg = ch - row * 12;
        *(uint4v*)(Plds + row * 104 + seg * 8) = *(const uint4v*)(P + ch * 8);
    }
    int rofs[13];
    #pragma unroll
    for (int nt = 0; nt < 13; nt++) {
        int r = nt * 16 + m; if (r > 195) r = 195;
        rofs[nt] = r * 104;
    }
    __syncthreads();

    for (int bi = 0; bi < 8; bi++) {
        const bf16* T = Tt + (size_t)(bg * 8 + bi) * (128 * 96);
        f32x4 acc[2][13] = {};
        #pragma unroll
        for (int kk = 0; kk < 96; kk += 32) {
            bf16x8 a0 = *(const bf16x8*)(T + (size_t)(w * 32 + m) * 96 + kk + quad * 8);
            bf16x8 a1 = *(const bf16x8*)(T + (size_t)(w * 32 + 16 + m) * 96 + kk + quad * 8);
            #pragma unroll
            for (int nt = 0; nt < 13; nt++) {
                bf16x8 bb = *(const bf16x8*)(Plds + rofs[nt] + kk + quad * 8);
                acc[0][nt] = MFMA16(a0, bb, acc[0][nt]);
                acc[1][nt] = MFMA16(a1, bb, acc[1][nt]);
            }
        }
        float mx = -3.4e38f;
        #pragma unroll
        for (int mt = 0; mt < 2; mt++)
            #pragma unroll
            for (int nt = 0; nt < 13; nt++)
                #pragma unroll
                for (int r = 0; r < 4; r++) mx = fmaxf(mx, acc[mt][nt][r]);
        #pragma unroll
        for (int dd = 1; dd < 64; dd <<= 1) mx = fmaxf(mx, __shfl_xor(mx, dd));
        if (lane == 0) red[bi][w] = mx;
    }
    __syncthreads();

    // fused epilogue: wave w handles bi = w and bi = w+4
    #pragma unroll
    for (int half = 0; half < 2; half++) {
        int bi = w + half * 4;
        int i  = bg * 8 + bi;          // b row
        int pr = i * 64 + c;
        float scll = fmaxf(fmaxf(red[bi][0], red[bi][1]), fmaxf(red[bi][2], red[bi][3]));
        bool act = lane < 48;
        float c0 = 0, c1 = 0, t0 = 0, t1 = 0;
        float dj0 = 0, dj1 = 0, di0 = 0, di1 = 0, v0 = 0, v1 = 0, g0 = 0, g1 = 0, bb0 = 0, bb1 = 0;
        if (act) {
            f32x2 cc  = *(const f32x2*)(Ctx + (size_t)pr * 96 + lane * 2);
            f32x2 tt  = *(const f32x2*)(t + i * 96 + lane * 2);
            f32x2 ddj = *(const f32x2*)(d + c * 96 + lane * 2);
            f32x2 ddi = *(const f32x2*)(d + i * 96 + lane * 2);
            f32x2 vv  = *(const f32x2*)(v + c * 96 + lane * 2);
            f32x2 gg  = *(const f32x2*)(ln_g + lane * 2);
            f32x2 bbv = *(const f32x2*)(ln_b + lane * 2);
            c0 = cc[0]; c1 = cc[1]; t0 = tt[0]; t1 = tt[1];
            dj0 = ddj[0]; dj1 = ddj[1]; di0 = ddi[0]; di1 = ddi[1];
            v0 = vv[0]; v1 = vv[1];
            g0 = gg[0]; g1 = gg[1]; bb0 = bbv[0]; bb1 = bbv[1];
        }
        float s = c0 + c1;
        #pragma unroll
        for (int k = 1; k < 64; k <<= 1) s += __shfl_xor(s, k);
        float mean = s * (1.0f / 96.0f);
        float e0 = act ? (c0 - mean) : 0.0f;
        float e1 = act ? (c1 - mean) : 0.0f;
        float q = e0 * e0 + e1 * e1;
        #pragma unroll
        for (int k = 1; k < 64; k <<= 1) q += __shfl_xor(q, k);
        float rstd = rsqrtf(q * (1.0f / 96.0f) + 1e-5f);
        float y0 = act ? (e0 * rstd * g0 + bb0) : 0.0f;
        float y1 = act ? (e1 * rstd * g1 + bb1) : 0.0f;
        float dot = y0 * di0 + y1 * di1;   // S_TGL uses d_i
        float ssq = y0 * y0 + y1 * y1;
        float tg  = t0 * dj0 + t1 * dj1;   // S_TGG uses d_j
        float cg  = t0 * v0 + t1 * v1;
        #pragma unroll
        for (int k = 1; k < 64; k <<= 1) {
            dot += __shfl_xor(dot, k); ssq += __shfl_xor(ssq, k);
            tg  += __shfl_xor(tg, k);  cg  += __shfl_xor(cg, k);
        }
        if (lane == 0) {
            float stgl = dot / fmaxf(sqrtf(ssq), 1e-6f);
            out[pr] = 0.5f * (tg + stgl) + 0.5f * (cg + scll);
        }
    }
}

// ---------------- launch ----------------

extern "C" void kernel_launch(void* const* d_in, const int* in_sizes, int n_in,
                              void* d_out, int out_size, void* d_ws, size_t ws_size,
                              hipStream_t stream)
{
    (void)in_sizes; (void)n_in; (void)out_size; (void)ws_size;
    char* ws = (char*)d_ws;
    float* t     = (float*)(ws + 0);               // 64*96 f32
    float* d     = (float*)(ws + 24576);
    float* v     = (float*)(ws + 49152);
    bf16* Wb = (bf16*)(ws + 106496);               // 8*96*512 bf16
    bf16* Qb = (bf16*)(ws + 892928);               // 8192*96 bf16
    bf16* Kb = (bf16*)(ws + 892928 + 1572864);
    bf16* Vb = (bf16*)(ws + 892928 + 2 * 1572864);
    bf16* Tt = (bf16*)(ws + 892928 + 3 * 1572864);
    bf16* Vp = (bf16*)(ws + 892928 + 4 * 1572864);         // 12544*96 bf16 = 2408448 B
    float* Ctx = (float*)(ws + 892928 + 4 * 1572864 + 2408448); // 4096*96 f32

    WPtrs wp;
    wp.W[0] = (const float*)d_in[6];   // W_t_cls
    wp.W[1] = (const float*)d_in[8];   // W_d_cls
    wp.W[2] = (const float*)d_in[10];  // W_v_cls
    wp.W[3] = (const float*)d_in[16];  // W_tgl_q
    wp.W[4] = (const float*)d_in[18];  // W_tgl_k
    wp.W[5] = (const float*)d_in[20];  // W_tgl_v
    wp.W[6] = (const float*)d_in[12];  // W_t_tok
    wp.W[7] = (const float*)d_in[14];  // W_v_patch
    hipLaunchKernelGGL(cvtw_kernel, dim3(384), dim3(256), 0, stream, wp, Wb);

    ProjParams pp;
    pp.Wb = Wb;
    pp.src[0] = (const float*)d_in[2];  pp.B[0] = (const float*)d_in[7];  pp.dst[0] = t;   // t_cls
    pp.src[1] = (const float*)d_in[0];  pp.B[1] = (const float*)d_in[9];  pp.dst[1] = d;   // d_cls
    pp.src[2] = (const float*)d_in[4];  pp.B[2] = (const float*)d_in[11]; pp.dst[2] = v;   // v_cls
    pp.src[3] = (const float*)d_in[1];  pp.B[3] = (const float*)d_in[17]; pp.dst[3] = Qb;  // Q (scaled)
    pp.src[4] = (const float*)d_in[3];  pp.B[4] = (const float*)d_in[19]; pp.dst[4] = Kb;  // K
    pp.src[5] = (const float*)d_in[3];  pp.B[5] = (const float*)d_in[21]; pp.dst[5] = Vb;  // V
    pp.src[6] = (const float*)d_in[3];  pp.B[6] = (const float*)d_in[13]; pp.dst[6] = Tt;  // t_tok
    pp.src[7] = (const float*)d_in[5];  pp.B[7] = (const float*)d_in[15]; pp.dst[7] = Vp;  // v_patch
    hipLaunchKernelGGL(proj_kernel, dim3(1422), dim3(256), 0, stream, pp);

    hipLaunchKernelGGL(attn_kernel, dim3(4096), dim3(256), 0, stream,
                       (const bf16*)Qb, (const bf16*)Kb, (const bf16*)Vb, Ctx);
    hipLaunchKernelGGL(cll_kernel, dim3(512), dim3(256), 0, stream,
                       (const bf16*)Tt, (const bf16*)Vp,
                       (const float*)Ctx, (const float*)t, (const float*)d, (const float*)v,
                       (const float*)d_in[22], (const float*)d_in[23], (float*)d_out);
}